// Round 8
// baseline (584.496 us; speedup 1.0000x reference)
//
#include <hip/hip_runtime.h>

#define DIMM 768
#define NH 12
#define HD 64
#define LSEQ 1024
#define BATCH 4
#define NXE 3145728   // 4096*768
#define NWE 589824    // 768*768

typedef __bf16 bf16x8 __attribute__((ext_vector_type(8)));
typedef float f32x4 __attribute__((ext_vector_type(4)));
typedef unsigned short u16;

static __device__ __forceinline__ u16 f2bf(float f) {
  unsigned u = __builtin_bit_cast(unsigned, f);
  u += 0x7fffu + ((u >> 16) & 1u);
  return (u16)(u >> 16);
}
static __device__ __forceinline__ float bf2f(u16 h) {
  unsigned u = ((unsigned)h) << 16;
  return __builtin_bit_cast(float, u);
}
static __device__ __forceinline__ bf16x8 ld8bf(const u16* p) {
  uint4 u = *(const uint4*)p;
  return __builtin_bit_cast(bf16x8, u);
}
#define MFMA(a, b, c) __builtin_amdgcn_mfma_f32_16x16x32_bf16(a, b, c, 0, 0, 0)
#define LGKM0_FENCE()                                      \
  do {                                                     \
    asm volatile("s_waitcnt lgkmcnt(0)" ::: "memory");     \
    __builtin_amdgcn_sched_barrier(0);                     \
    __builtin_amdgcn_s_barrier();                          \
  } while (0)

// ---------- Kernel 0: fp32 -> bf16 hi/lo conversion prepass ----------
__global__ __launch_bounds__(256) void convert(
    const float* __restrict__ q_in, const float* __restrict__ k_in,
    const float* __restrict__ v_in, const float* __restrict__ Wq,
    const float* __restrict__ Wk, const float* __restrict__ Wv,
    const float* __restrict__ Wp, u16* __restrict__ AqH, u16* __restrict__ AqL,
    u16* __restrict__ AkH, u16* __restrict__ AkL, u16* __restrict__ Av,
    u16* __restrict__ WqH, u16* __restrict__ WqL, u16* __restrict__ WkH,
    u16* __restrict__ WkL, u16* __restrict__ Wvr, u16* __restrict__ Wpr) {
  long i = ((long)blockIdx.x * 256 + threadIdx.x) * 4;
  const float* src;
  u16 *dh, *dl = nullptr;
  long off;
  if (i < NXE) { src = q_in; dh = AqH; dl = AqL; off = i; }
  else if (i < 2L * NXE) { src = k_in; dh = AkH; dl = AkL; off = i - NXE; }
  else if (i < 3L * NXE) { src = v_in; dh = Av; off = i - 2L * NXE; }
  else {
    long j = i - 3L * NXE;
    int which = (int)(j / NWE);
    off = j % NWE;
    if (which == 0) { src = Wq; dh = WqH; dl = WqL; }
    else if (which == 1) { src = Wk; dh = WkH; dl = WkL; }
    else if (which == 2) { src = Wv; dh = Wvr; }
    else { src = Wp; dh = Wpr; }
  }
  float4 v = *(const float4*)(src + off);
  ushort4 h;
  h.x = f2bf(v.x); h.y = f2bf(v.y); h.z = f2bf(v.z); h.w = f2bf(v.w);
  *(ushort4*)(dh + off) = h;
  if (dl) {
    ushort4 lo;
    lo.x = f2bf(v.x - bf2f(h.x)); lo.y = f2bf(v.y - bf2f(h.y));
    lo.z = f2bf(v.z - bf2f(h.z)); lo.w = f2bf(v.w - bf2f(h.w));
    *(ushort4*)(dl + off) = lo;
  }
}

// ---------- GEMM body: 64x128 tile, reg-staged, DOUBLE-buffered LDS ----
// (unchanged from round 7 best)
__device__ __forceinline__ void gemm_body(
    int mode, const u16* AqH, const u16* AqL, const u16* AkH, const u16* AkL,
    const u16* Av, const u16* WqH, const u16* WqL, const u16* WkH,
    const u16* WkL, const u16* Wvr, const u16* Wpr, const u16* wbuf,
    u16* qhi, u16* qlo, u16* khi, u16* klo, u16* vT, float* outp,
    const float* bias) {
  __shared__ u16 sAh[2][64 * 32], sAl[2][64 * 32];    // 2 x 4 KB each
  __shared__ u16 sBh[2][128 * 32], sBl[2][128 * 32];  // 2 x 8 KB each
  const u16 *Ah, *Al = nullptr, *Bh, *Bl = nullptr;
  if (mode == 0) { Ah = AqH; Al = AqL; Bh = WqH; Bl = WqL; }
  else if (mode == 1) { Ah = AkH; Al = AkL; Bh = WkH; Bl = WkL; }
  else if (mode == 2) { Ah = Av; Bh = Wvr; }
  else { Ah = wbuf; Bh = Wpr; }
  const int t = threadIdx.x, w = t >> 6, l = t & 63;
  const int quad = l >> 4, l15 = l & 15;
  // XCD swizzle: 384 blocks/mode, 8 XCDs, 48 contiguous per XCD (bijective)
  const int flat = blockIdx.x + 64 * blockIdx.y;
  const int swz = (flat & 7) * 48 + (flat >> 3);
  const int m0 = (swz & 63) * 64, n0 = (swz >> 6) * 128;
  const int wm = (w & 1) * 32, wn = (w >> 1) * 64;
  const int srow = t >> 2, scol = (t & 3) * 8;
  const int t8 = t * 8;  // staging slot (u16 index)
  const u16* gA = Ah + (m0 + srow) * DIMM + scol;
  const u16* gB = Bh + (n0 + srow) * DIMM + scol;
  const u16* gAl = (mode < 2) ? Al + (m0 + srow) * DIMM + scol : nullptr;
  const u16* gBl = (mode < 2) ? Bl + (n0 + srow) * DIMM + scol : nullptr;
  f32x4 acc[2][4] = {};
  uint4 rA, rB0, rB1, rAl, rBl0, rBl1;

  if (mode < 2) {
#define LOADS2(k0n)                                                  \
    do {                                                             \
      rA = *(const uint4*)(gA + (k0n));                              \
      rB0 = *(const uint4*)(gB + (k0n));                             \
      rB1 = *(const uint4*)(gB + 64 * DIMM + (k0n));                 \
      rAl = *(const uint4*)(gAl + (k0n));                            \
      rBl0 = *(const uint4*)(gBl + (k0n));                           \
      rBl1 = *(const uint4*)(gBl + 64 * DIMM + (k0n));               \
    } while (0)
#define DSW2(p)                                                      \
    do {                                                             \
      *(uint4*)(&sAh[p][t8]) = rA;                                   \
      *(uint4*)(&sBh[p][t8]) = rB0;                                  \
      *(uint4*)(&sBh[p][t8 + 2048]) = rB1;                           \
      *(uint4*)(&sAl[p][t8]) = rAl;                                  \
      *(uint4*)(&sBl[p][t8]) = rBl0;                                 \
      *(uint4*)(&sBl[p][t8 + 2048]) = rBl1;                          \
    } while (0)
#define FRAGS2(p)                                                    \
    do {                                                             \
      _Pragma("unroll") for (int i = 0; i < 2; ++i) {                \
        ah[i] = __builtin_bit_cast(bf16x8,                           \
            *(const uint4*)(&sAh[p][(wm + i * 16 + l15) * 32 + quad * 8])); \
        al[i] = __builtin_bit_cast(bf16x8,                           \
            *(const uint4*)(&sAl[p][(wm + i * 16 + l15) * 32 + quad * 8])); \
      }                                                              \
      _Pragma("unroll") for (int j = 0; j < 4; ++j) {                \
        bh[j] = __builtin_bit_cast(bf16x8,                           \
            *(const uint4*)(&sBh[p][(wn + j * 16 + l15) * 32 + quad * 8])); \
        bl[j] = __builtin_bit_cast(bf16x8,                           \
            *(const uint4*)(&sBl[p][(wn + j * 16 + l15) * 32 + quad * 8])); \
      }                                                              \
    } while (0)
#define MFMAS2()                                                     \
    do {                                                             \
      _Pragma("unroll") for (int i = 0; i < 2; ++i)                  \
        _Pragma("unroll") for (int j = 0; j < 4; ++j)                \
          acc[i][j] = MFMA(ah[i], bh[j], acc[i][j]);                 \
      _Pragma("unroll") for (int i = 0; i < 2; ++i)                  \
        _Pragma("unroll") for (int j = 0; j < 4; ++j)                \
          acc[i][j] = MFMA(al[i], bh[j], acc[i][j]);                 \
      _Pragma("unroll") for (int i = 0; i < 2; ++i)                  \
        _Pragma("unroll") for (int j = 0; j < 4; ++j)                \
          acc[i][j] = MFMA(ah[i], bl[j], acc[i][j]);                 \
    } while (0)
    LOADS2(0);
    DSW2(0);      // chunk 0 -> buf0 (compiler-counted vmcnt waits)
    LOADS2(32);   // chunk 1 in flight across the fence
    LGKM0_FENCE();
    for (int k0 = 0; k0 < DIMM; k0 += 64) {
      bf16x8 ah[2], al[2], bh[4], bl[4];
      // half A: compute chunk k0 from buf0; stage chunk k0+32 -> buf1
      FRAGS2(0);
      DSW2(1);
      if (k0 + 64 < DIMM) LOADS2(k0 + 64);
      MFMAS2();
      LGKM0_FENCE();
      // half B: compute chunk k0+32 from buf1; stage chunk k0+64 -> buf0
      FRAGS2(1);
      if (k0 + 64 < DIMM) {
        DSW2(0);
        if (k0 + 96 < DIMM) LOADS2(k0 + 96);
      }
      MFMAS2();
      if (k0 + 64 < DIMM) LGKM0_FENCE();
    }
#undef LOADS2
#undef DSW2
#undef FRAGS2
#undef MFMAS2
  } else {
#define LOADS1(k0n)                                                  \
    do {                                                             \
      rA = *(const uint4*)(gA + (k0n));                              \
      rB0 = *(const uint4*)(gB + (k0n));                             \
      rB1 = *(const uint4*)(gB + 64 * DIMM + (k0n));                 \
    } while (0)
#define DSW1(p)                                                      \
    do {                                                             \
      *(uint4*)(&sAh[p][t8]) = rA;                                   \
      *(uint4*)(&sBh[p][t8]) = rB0;                                  \
      *(uint4*)(&sBh[p][t8 + 2048]) = rB1;                           \
    } while (0)
#define FRAGS1(p)                                                    \
    do {                                                             \
      _Pragma("unroll") for (int i = 0; i < 2; ++i)                  \
        ah[i] = __builtin_bit_cast(bf16x8,                           \
            *(const uint4*)(&sAh[p][(wm + i * 16 + l15) * 32 + quad * 8])); \
      _Pragma("unroll") for (int j = 0; j < 4; ++j)                  \
        bh[j] = __builtin_bit_cast(bf16x8,                           \
            *(const uint4*)(&sBh[p][(wn + j * 16 + l15) * 32 + quad * 8])); \
    } while (0)
#define MFMAS1()                                                     \
    do {                                                             \
      _Pragma("unroll") for (int i = 0; i < 2; ++i)                  \
        _Pragma("unroll") for (int j = 0; j < 4; ++j)                \
          acc[i][j] = MFMA(ah[i], bh[j], acc[i][j]);                 \
    } while (0)
    LOADS1(0);
    DSW1(0);
    LOADS1(32);
    LGKM0_FENCE();
    for (int k0 = 0; k0 < DIMM; k0 += 64) {
      bf16x8 ah[2], bh[4];
      FRAGS1(0);
      DSW1(1);
      if (k0 + 64 < DIMM) LOADS1(k0 + 64);
      MFMAS1();
      LGKM0_FENCE();
      FRAGS1(1);
      if (k0 + 64 < DIMM) {
        DSW1(0);
        if (k0 + 96 < DIMM) LOADS1(k0 + 96);
      }
      MFMAS1();
      if (k0 + 64 < DIMM) LGKM0_FENCE();
    }
#undef LOADS1
#undef DSW1
#undef FRAGS1
#undef MFMAS1
  }

  u16* oh = (mode == 0) ? qhi : khi;
  u16* ol = (mode == 0) ? qlo : klo;
#pragma unroll
  for (int i = 0; i < 2; ++i)
#pragma unroll
    for (int j = 0; j < 4; ++j)
#pragma unroll
      for (int r = 0; r < 4; ++r) {
        int grow = m0 + wm + i * 16 + quad * 4 + r;  // (b,l)
        int gcol = n0 + wn + j * 16 + l15;           // (h,d)
        float c = acc[i][j][r];
        int b = grow >> 10, ll = grow & 1023, h = gcol >> 6, d = gcol & 63;
        if (mode < 2) {
          int idx = ((b * NH + h) * LSEQ + ll) * HD + d;
          u16 hi = f2bf(c);
          oh[idx] = hi;
          ol[idx] = f2bf(c - bf2f(hi));
        } else if (mode == 2) {
          vT[((b * NH + h) * HD + d) * LSEQ + ll] = f2bf(c);
        } else {
          outp[grow * DIMM + gcol] = c + bias[gcol];
        }
      }
}

__global__ __launch_bounds__(256, 3) void gemm_qkv(
    const u16* __restrict__ AqH, const u16* __restrict__ AqL,
    const u16* __restrict__ AkH, const u16* __restrict__ AkL,
    const u16* __restrict__ Av, const u16* __restrict__ WqH,
    const u16* __restrict__ WqL, const u16* __restrict__ WkH,
    const u16* __restrict__ WkL, const u16* __restrict__ Wvr,
    const u16* __restrict__ Wpr, const u16* __restrict__ wbuf,
    u16* __restrict__ qhi, u16* __restrict__ qlo, u16* __restrict__ khi,
    u16* __restrict__ klo, u16* __restrict__ vT, float* __restrict__ outp,
    const float* __restrict__ bias) {
  gemm_body(blockIdx.z, AqH, AqL, AkH, AkL, Av, WqH, WqL, WkH, WkL, Wvr, Wpr,
            wbuf, qhi, qlo, khi, klo, vT, outp, bias);
}

__global__ __launch_bounds__(256, 3) void gemm_proj(
    const u16* __restrict__ AqH, const u16* __restrict__ AqL,
    const u16* __restrict__ AkH, const u16* __restrict__ AkL,
    const u16* __restrict__ Av, const u16* __restrict__ WqH,
    const u16* __restrict__ WqL, const u16* __restrict__ WkH,
    const u16* __restrict__ WkL, const u16* __restrict__ Wvr,
    const u16* __restrict__ Wpr, const u16* __restrict__ wbuf,
    u16* __restrict__ qhi, u16* __restrict__ qlo, u16* __restrict__ khi,
    u16* __restrict__ klo, u16* __restrict__ vT, float* __restrict__ outp,
    const float* __restrict__ bias) {
  gemm_body(3, AqH, AqL, AkH, AkL, Av, WqH, WqL, WkH, WkL, Wvr, Wpr,
            wbuf, qhi, qlo, khi, klo, vT, outp, bias);
}

// ---------- Kernel 2: attention core, barrier-free phase 1 --------------
// K fragments read DIRECTLY from global (per-wave-owned rows; no LDS, no
// fences in phase 1). The XCD swizzle (r2) keeps each (b,h)'s K/vT on one
// XCD's L2: concurrent working set ~1-3 groups x 384 KB << 4 MiB, so the
// r1 thrash (which had NO swizzle) should not recur. HYPOTHESIS TEST:
// FETCH_SIZE must stay ~18-30 MB; >100 MB falsifies co-location theory.
__global__ __launch_bounds__(256, 3) void attn_core(
    const u16* __restrict__ qhi, const u16* __restrict__ qlo,
    const u16* __restrict__ khi, const u16* __restrict__ klo,
    const u16* __restrict__ vT, const float* __restrict__ relk,
    const float* __restrict__ relv, float* __restrict__ attn_out,
    u16* __restrict__ wbuf) {
  // Pb[16][1032] bf16 (33 KB) -- P staging for attn store + PV A-operand
  __shared__ __align__(16) u16 uni[16 * 1032];
  __shared__ float qrel[16][7];
  __shared__ float arel[16][7];
  __shared__ float rvt[7][64];
  __shared__ float red[4][16][4];

  // XCD-aware swizzle: 3072 blocks, 8 XCDs, 384 contiguous per XCD so
  // blocks sharing K/vT (same b,h) co-locate on one XCD's L2.
  const int Lb = blockIdx.x + 64 * (blockIdx.y + NH * blockIdx.z);
  const int flat = (Lb & 7) * 384 + (Lb >> 3);
  const int qt = flat & 63, h = (flat >> 6) % NH, b = flat / (64 * NH);
  const int q0 = qt * 16;
  const int tid = threadIdx.x, wave = tid >> 6, lane = tid & 63;
  const int quad = lane >> 4, l15 = lane & 15;
  const int bhd = b * NH + h;

  // Q fragments issue first; latency hides under phase 0's qrel compute.
  const int qbase = (bhd * LSEQ + q0 + l15) * HD + quad * 8;
  bf16x8 ah0 = ld8bf(qhi + qbase);
  bf16x8 ah1 = ld8bf(qhi + qbase + 32);
  bf16x8 al0 = ld8bf(qlo + qbase);
  bf16x8 al1 = ld8bf(qlo + qbase + 32);

  // phase 0: rel_v -> LDS; qrel (vectorized); zero arel
  for (int t = tid; t < 7 * HD; t += 256) rvt[t >> 6][t & 63] = relv[t];
  if (tid < 112) {
    int q = tid / 7, rr = tid % 7;
    const u16* qp = qhi + (bhd * LSEQ + q0 + q) * HD;
    const u16* lp = qlo + (bhd * LSEQ + q0 + q) * HD;
    const float* tp = relk + rr * HD;
    float s = 0.f;
#pragma unroll
    for (int d8 = 0; d8 < HD; d8 += 8) {
      uint4 uh = *(const uint4*)(qp + d8);
      uint4 ul = *(const uint4*)(lp + d8);
      float4 t0 = *(const float4*)(tp + d8);
      float4 t1 = *(const float4*)(tp + d8 + 4);
      unsigned hh[4] = {uh.x, uh.y, uh.z, uh.w};
      unsigned lv[4] = {ul.x, ul.y, ul.z, ul.w};
      float tv[8] = {t0.x, t0.y, t0.z, t0.w, t1.x, t1.y, t1.z, t1.w};
#pragma unroll
      for (int m = 0; m < 4; ++m) {
        s += (bf2f((u16)(hh[m] & 0xffff)) + bf2f((u16)(lv[m] & 0xffff))) * tv[2 * m];
        s += (bf2f((u16)(hh[m] >> 16)) + bf2f((u16)(lv[m] >> 16))) * tv[2 * m + 1];
      }
    }
    qrel[q][rr] = s;
    arel[q][rr] = 0.f;
  }

  // phase 1: S = Q K^T (hi/lo 3-term); K read directly from global.
  // Lane supplies K[c*64 + wave*16 + l15][quad*8 + {0,32} ..+8): per-wave-
  // owned rows, zero barriers, compiler-pipelined loads (unroll 4 keeps
  // ~16 loads in flight).
  f32x4 sc[16];
  {
    const u16* gh = khi + (bhd * LSEQ + wave * 16 + l15) * HD + quad * 8;
    const u16* gl = klo + (bhd * LSEQ + wave * 16 + l15) * HD + quad * 8;
#pragma unroll 4
    for (int c = 0; c < 16; ++c) {
      const u16* ph = gh + c * (64 * HD);
      const u16* pl = gl + c * (64 * HD);
      bf16x8 kh0 = ld8bf(ph);
      bf16x8 kh1 = ld8bf(ph + 32);
      bf16x8 kl0 = ld8bf(pl);
      bf16x8 kl1 = ld8bf(pl + 32);
      f32x4 e = {}, f = {};
      e = MFMA(ah0, kh0, e);
      f = MFMA(ah1, kh1, f);
      e = MFMA(ah0, kl0, e);
      f = MFMA(ah1, kl1, f);
      e = MFMA(al0, kh0, e);
      f = MFMA(al1, kh1, f);
      sc[c] = e + f;
    }
  }
  __syncthreads();  // phase-0 qrel/arel/rvt writes visible before phase 1.5

  // phase 1.5: + rel scores, *8; per-row max
  const int colbase = wave * 16 + l15;        // col = colbase + c*64
  const int dbase = colbase - q0 - quad * 4;  // d = dbase + c*64 - r
  float mrow[4] = {-3.4e38f, -3.4e38f, -3.4e38f, -3.4e38f};
#pragma unroll
  for (int c = 0; c < 16; ++c)
#pragma unroll
    for (int r = 0; r < 4; ++r) {
      int d = dbase + c * 64 - r;
      int ri = d < -3 ? 0 : (d > 3 ? 6 : d + 3);
      float s = (sc[c][r] + qrel[quad * 4 + r][ri]) * 8.0f;
      sc[c][r] = s;
      mrow[r] = fmaxf(mrow[r], s);
    }
#pragma unroll
  for (int m = 1; m <= 8; m <<= 1)
#pragma unroll
    for (int r = 0; r < 4; ++r) mrow[r] = fmaxf(mrow[r], __shfl_xor(mrow[r], m));
  if (l15 < 4) {
    float mv = l15 == 0 ? mrow[0] : l15 == 1 ? mrow[1] : l15 == 2 ? mrow[2] : mrow[3];
    red[0][quad * 4 + l15][wave] = mv;
  }
  __syncthreads();
  float mx[4];
#pragma unroll
  for (int r = 0; r < 4; ++r) {
    int row = quad * 4 + r;
    mx[r] = fmaxf(fmaxf(red[0][row][0], red[0][row][1]),
                  fmaxf(red[0][row][2], red[0][row][3]));
  }

  // phase 2: exp + partial sums (total, d<=-3, d>=3)
  float sum[4] = {}, s0a[4] = {}, s6a[4] = {};
#pragma unroll
  for (int c = 0; c < 16; ++c)
#pragma unroll
    for (int r = 0; r < 4; ++r) {
      float e = __expf(sc[c][r] - mx[r]);
      sc[c][r] = e;
      int d = dbase + c * 64 - r;
      sum[r] += e;
      if (d <= -3) s0a[r] += e;
      if (d >= 3) s6a[r] += e;
    }
#pragma unroll
  for (int m = 1; m <= 8; m <<= 1)
#pragma unroll
    for (int r = 0; r < 4; ++r) {
      sum[r] += __shfl_xor(sum[r], m);
      s0a[r] += __shfl_xor(s0a[r], m);
      s6a[r] += __shfl_xor(s6a[r], m);
    }
  if (l15 < 4) {
    int row = quad * 4 + l15;
    float sv = l15 == 0 ? sum[0] : l15 == 1 ? sum[1] : l15 == 2 ? sum[2] : sum[3];
    float a0 = l15 == 0 ? s0a[0] : l15 == 1 ? s0a[1] : l15 == 2 ? s0a[2] : s0a[3];
    float a6 = l15 == 0 ? s6a[0] : l15 == 1 ? s6a[1] : l15 == 2 ? s6a[2] : s6a[3];
    red[1][row][wave] = sv;
    red[2][row][wave] = a0;
    red[3][row][wave] = a6;
  }
  __syncthreads();
  float rn[4];
#pragma unroll
  for (int r = 0; r < 4; ++r) {
    int row = quad * 4 + r;
    float s = red[1][row][0] + red[1][row][1] + red[1][row][2] + red[1][row][3];
    rn[r] = 1.0f / s;
    if (wave == 0 && l15 == 0) {
      float t0 = red[2][row][0] + red[2][row][1] + red[2][row][2] + red[2][row][3];
      float t6 = red[3][row][0] + red[3][row][1] + red[3][row][2] + red[3][row][3];
      arel[row][0] = t0 * rn[r];
      arel[row][6] = t6 * rn[r];
    }
  }

  // phase 2c: normalize -> Pb (bf16, LDS) + singleton buckets
#pragma unroll
  for (int c = 0; c < 16; ++c) {
    int col = colbase + c * 64;
#pragma unroll
    for (int r = 0; r < 4; ++r) {
      int row = quad * 4 + r;
      float p = sc[c][r] * rn[r];
      uni[row * 1032 + col] = f2bf(p);
      int d = dbase + c * 64 - r;
      if (d >= -2 && d <= 2) arel[row][d + 3] = p;
    }
  }
  __syncthreads();

  // phase 2d: coalesced fp32 attn store from Pb (float4/thread/row)
  {
    float* aob = attn_out + ((size_t)(bhd * LSEQ + q0)) * LSEQ;
#pragma unroll
    for (int row = 0; row < 16; ++row) {
      uint2 u = *(const uint2*)&uni[row * 1032 + tid * 4];
      float4 f = {bf2f((u16)(u.x & 0xffff)), bf2f((u16)(u.x >> 16)),
                  bf2f((u16)(u.y & 0xffff)), bf2f((u16)(u.y >> 16))};
      *(float4*)(aob + row * LSEQ + tid * 4) = f;
    }
  }

  // phase 3: W1 = P @ V (wave -> 16 d-cols) + W2 = arel @ rel_v
  {
    const u16* vb = vT + (bhd * HD + wave * 16 + l15) * LSEQ;
    f32x4 acc0 = {}, acc1 = {};
#pragma unroll 4
    for (int kk = 0; kk < LSEQ; kk += 64) {
      int ak = kk + quad * 8;
      bf16x8 aP0 = __builtin_bit_cast(bf16x8, *(const uint4*)&uni[l15 * 1032 + ak]);
      bf16x8 bV0 = ld8bf(vb + ak);
      acc0 = MFMA(aP0, bV0, acc0);
      bf16x8 aP1 = __builtin_bit_cast(bf16x8, *(const uint4*)&uni[l15 * 1032 + ak + 32]);
      bf16x8 bV1 = ld8bf(vb + ak + 32);
      acc1 = MFMA(aP1, bV1, acc1);
    }
    f32x4 acc = acc0 + acc1;
    const int col = wave * 16 + l15;  // d
#pragma unroll
    for (int r = 0; r < 4; ++r) {
      int row = quad * 4 + r;  // q within tile
      float w2 = 0.f;
#pragma unroll
      for (int t = 0; t < 7; ++t) w2 += arel[row][t] * rvt[t][col];
      wbuf[(b * LSEQ + q0 + row) * DIMM + h * HD + col] = f2bf(acc[r] + w2);
    }
  }
}

extern "C" void kernel_launch(void* const* d_in, const int* in_sizes, int n_in,
                              void* d_out, int out_size, void* d_ws, size_t ws_size,
                              hipStream_t stream) {
  const float* q_in = (const float*)d_in[0];
  const float* k_in = (const float*)d_in[1];
  const float* v_in = (const float*)d_in[2];
  const float* Wq = (const float*)d_in[3];
  const float* Wk = (const float*)d_in[4];
  const float* Wv = (const float*)d_in[5];
  const float* Wp = (const float*)d_in[6];
  const float* bias = (const float*)d_in[7];
  const float* relk = (const float*)d_in[8];
  const float* relv = (const float*)d_in[9];
  float* out = (float*)d_out;

  u16* p = (u16*)d_ws;
  u16 *AqH = p, *AqL = AqH + NXE, *AkH = AqL + NXE, *AkL = AkH + NXE,
      *Av = AkL + NXE;
  u16 *WqH = Av + NXE, *WqL = WqH + NWE, *WkH = WqL + NWE, *WkL = WkH + NWE,
      *Wvr = WkL + NWE, *Wpr = Wvr + NWE;
  u16 *qhi = Wpr + NWE, *qlo = qhi + NXE, *khi = qlo + NXE, *klo = khi + NXE,
      *vT = klo + NXE, *wbuf = vT + NXE;

  convert<<<(3 * NXE + 4 * NWE) / 1024, 256, 0, stream>>>(
      q_in, k_in, v_in, Wq, Wk, Wv, Wp, AqH, AqL, AkH, AkL, Av, WqH, WqL, WkH,
      WkL, Wvr, Wpr);
  gemm_qkv<<<dim3(64, 6, 3), 256, 0, stream>>>(
      AqH, AqL, AkH, AkL, Av, WqH, WqL, WkH, WkL, Wvr, Wpr, wbuf, qhi, qlo,
      khi, klo, vT, out, bias);
  attn_core<<<dim3(64, NH, BATCH), 256, 0, stream>>>(
      qhi, qlo, khi, klo, vT, relk, relv, out + NXE, wbuf);
  gemm_proj<<<dim3(64, 6, 1), 256, 0, stream>>>(
      AqH, AqL, AkH, AkL, Av, WqH, WqL, WkH, WkL, Wvr, Wpr, wbuf, qhi, qlo,
      khi, klo, vT, out, bias);
}

// Round 9
// 426.525 us; speedup vs baseline: 1.3704x; 1.3704x over previous
//
#include <hip/hip_runtime.h>

#define DIMM 768
#define NH 12
#define HD 64
#define LSEQ 1024
#define BATCH 4
#define NXE 3145728   // 4096*768
#define NWE 589824    // 768*768

typedef __bf16 bf16x8 __attribute__((ext_vector_type(8)));
typedef float f32x4 __attribute__((ext_vector_type(4)));
typedef unsigned short u16;

static __device__ __forceinline__ u16 f2bf(float f) {
  unsigned u = __builtin_bit_cast(unsigned, f);
  u += 0x7fffu + ((u >> 16) & 1u);
  return (u16)(u >> 16);
}
static __device__ __forceinline__ float bf2f(u16 h) {
  unsigned u = ((unsigned)h) << 16;
  return __builtin_bit_cast(float, u);
}
static __device__ __forceinline__ bf16x8 ld8bf(const u16* p) {
  uint4 u = *(const uint4*)p;
  return __builtin_bit_cast(bf16x8, u);
}
#define MFMA(a, b, c) __builtin_amdgcn_mfma_f32_16x16x32_bf16(a, b, c, 0, 0, 0)
#define LGKM0_FENCE()                                      \
  do {                                                     \
    asm volatile("s_waitcnt lgkmcnt(0)" ::: "memory");     \
    __builtin_amdgcn_sched_barrier(0);                     \
    __builtin_amdgcn_s_barrier();                          \
  } while (0)

// ---------- Kernel 0: fp32 -> bf16 hi/lo conversion prepass ----------
__global__ __launch_bounds__(256) void convert(
    const float* __restrict__ q_in, const float* __restrict__ k_in,
    const float* __restrict__ v_in, const float* __restrict__ Wq,
    const float* __restrict__ Wk, const float* __restrict__ Wv,
    const float* __restrict__ Wp, u16* __restrict__ AqH, u16* __restrict__ AqL,
    u16* __restrict__ AkH, u16* __restrict__ AkL, u16* __restrict__ Av,
    u16* __restrict__ WqH, u16* __restrict__ WqL, u16* __restrict__ WkH,
    u16* __restrict__ WkL, u16* __restrict__ Wvr, u16* __restrict__ Wpr) {
  long i = ((long)blockIdx.x * 256 + threadIdx.x) * 4;
  const float* src;
  u16 *dh, *dl = nullptr;
  long off;
  if (i < NXE) { src = q_in; dh = AqH; dl = AqL; off = i; }
  else if (i < 2L * NXE) { src = k_in; dh = AkH; dl = AkL; off = i - NXE; }
  else if (i < 3L * NXE) { src = v_in; dh = Av; off = i - 2L * NXE; }
  else {
    long j = i - 3L * NXE;
    int which = (int)(j / NWE);
    off = j % NWE;
    if (which == 0) { src = Wq; dh = WqH; dl = WqL; }
    else if (which == 1) { src = Wk; dh = WkH; dl = WkL; }
    else if (which == 2) { src = Wv; dh = Wvr; }
    else { src = Wp; dh = Wpr; }
  }
  float4 v = *(const float4*)(src + off);
  ushort4 h;
  h.x = f2bf(v.x); h.y = f2bf(v.y); h.z = f2bf(v.z); h.w = f2bf(v.w);
  *(ushort4*)(dh + off) = h;
  if (dl) {
    ushort4 lo;
    lo.x = f2bf(v.x - bf2f(h.x)); lo.y = f2bf(v.y - bf2f(h.y));
    lo.z = f2bf(v.z - bf2f(h.z)); lo.w = f2bf(v.w - bf2f(h.w));
    *(ushort4*)(dl + off) = lo;
  }
}

// ---------- GEMM body: 64x128 tile, reg-staged, DOUBLE-buffered LDS ----
// One lgkm0+barrier per K-step. Per half-pair: ds_read buf[p] -> DSW staged
// regs -> buf[p^1] -> issue loads(k+2) -> MFMA -> fence. No vmcnt(0) drain
// anywhere; staged loads get a full K-step of cover.
__device__ __forceinline__ void gemm_body(
    int mode, const u16* AqH, const u16* AqL, const u16* AkH, const u16* AkL,
    const u16* Av, const u16* WqH, const u16* WqL, const u16* WkH,
    const u16* WkL, const u16* Wvr, const u16* Wpr, const u16* wbuf,
    u16* qhi, u16* qlo, u16* khi, u16* klo, u16* vT, float* outp,
    const float* bias) {
  __shared__ u16 sAh[2][64 * 32], sAl[2][64 * 32];    // 2 x 4 KB each
  __shared__ u16 sBh[2][128 * 32], sBl[2][128 * 32];  // 2 x 8 KB each
  const u16 *Ah, *Al = nullptr, *Bh, *Bl = nullptr;
  if (mode == 0) { Ah = AqH; Al = AqL; Bh = WqH; Bl = WqL; }
  else if (mode == 1) { Ah = AkH; Al = AkL; Bh = WkH; Bl = WkL; }
  else if (mode == 2) { Ah = Av; Bh = Wvr; }
  else { Ah = wbuf; Bh = Wpr; }
  const int t = threadIdx.x, w = t >> 6, l = t & 63;
  const int quad = l >> 4, l15 = l & 15;
  // XCD swizzle: 384 blocks/mode, 8 XCDs, 48 contiguous per XCD (bijective)
  const int flat = blockIdx.x + 64 * blockIdx.y;
  const int swz = (flat & 7) * 48 + (flat >> 3);
  const int m0 = (swz & 63) * 64, n0 = (swz >> 6) * 128;
  const int wm = (w & 1) * 32, wn = (w >> 1) * 64;
  const int srow = t >> 2, scol = (t & 3) * 8;
  const int t8 = t * 8;  // staging slot (u16 index)
  const u16* gA = Ah + (m0 + srow) * DIMM + scol;
  const u16* gB = Bh + (n0 + srow) * DIMM + scol;
  const u16* gAl = (mode < 2) ? Al + (m0 + srow) * DIMM + scol : nullptr;
  const u16* gBl = (mode < 2) ? Bl + (n0 + srow) * DIMM + scol : nullptr;
  f32x4 acc[2][4] = {};
  uint4 rA, rB0, rB1, rAl, rBl0, rBl1;

  if (mode < 2) {
#define LOADS2(k0n)                                                  \
    do {                                                             \
      rA = *(const uint4*)(gA + (k0n));                              \
      rB0 = *(const uint4*)(gB + (k0n));                             \
      rB1 = *(const uint4*)(gB + 64 * DIMM + (k0n));                 \
      rAl = *(const uint4*)(gAl + (k0n));                            \
      rBl0 = *(const uint4*)(gBl + (k0n));                           \
      rBl1 = *(const uint4*)(gBl + 64 * DIMM + (k0n));               \
    } while (0)
#define DSW2(p)                                                      \
    do {                                                             \
      *(uint4*)(&sAh[p][t8]) = rA;                                   \
      *(uint4*)(&sBh[p][t8]) = rB0;                                  \
      *(uint4*)(&sBh[p][t8 + 2048]) = rB1;                           \
      *(uint4*)(&sAl[p][t8]) = rAl;                                  \
      *(uint4*)(&sBl[p][t8]) = rBl0;                                 \
      *(uint4*)(&sBl[p][t8 + 2048]) = rBl1;                          \
    } while (0)
#define FRAGS2(p)                                                    \
    do {                                                             \
      _Pragma("unroll") for (int i = 0; i < 2; ++i) {                \
        ah[i] = __builtin_bit_cast(bf16x8,                           \
            *(const uint4*)(&sAh[p][(wm + i * 16 + l15) * 32 + quad * 8])); \
        al[i] = __builtin_bit_cast(bf16x8,                           \
            *(const uint4*)(&sAl[p][(wm + i * 16 + l15) * 32 + quad * 8])); \
      }                                                              \
      _Pragma("unroll") for (int j = 0; j < 4; ++j) {                \
        bh[j] = __builtin_bit_cast(bf16x8,                           \
            *(const uint4*)(&sBh[p][(wn + j * 16 + l15) * 32 + quad * 8])); \
        bl[j] = __builtin_bit_cast(bf16x8,                           \
            *(const uint4*)(&sBl[p][(wn + j * 16 + l15) * 32 + quad * 8])); \
      }                                                              \
    } while (0)
#define MFMAS2()                                                     \
    do {                                                             \
      _Pragma("unroll") for (int i = 0; i < 2; ++i)                  \
        _Pragma("unroll") for (int j = 0; j < 4; ++j)                \
          acc[i][j] = MFMA(ah[i], bh[j], acc[i][j]);                 \
      _Pragma("unroll") for (int i = 0; i < 2; ++i)                  \
        _Pragma("unroll") for (int j = 0; j < 4; ++j)                \
          acc[i][j] = MFMA(al[i], bh[j], acc[i][j]);                 \
      _Pragma("unroll") for (int i = 0; i < 2; ++i)                  \
        _Pragma("unroll") for (int j = 0; j < 4; ++j)                \
          acc[i][j] = MFMA(ah[i], bl[j], acc[i][j]);                 \
    } while (0)
    LOADS2(0);
    DSW2(0);      // chunk 0 -> buf0 (compiler-counted vmcnt waits)
    LOADS2(32);   // chunk 1 in flight across the fence
    LGKM0_FENCE();
    for (int k0 = 0; k0 < DIMM; k0 += 64) {
      bf16x8 ah[2], al[2], bh[4], bl[4];
      // half A: compute chunk k0 from buf0; stage chunk k0+32 -> buf1
      FRAGS2(0);
      DSW2(1);
      if (k0 + 64 < DIMM) LOADS2(k0 + 64);
      MFMAS2();
      LGKM0_FENCE();
      // half B: compute chunk k0+32 from buf1; stage chunk k0+64 -> buf0
      FRAGS2(1);
      if (k0 + 64 < DIMM) {
        DSW2(0);
        if (k0 + 96 < DIMM) LOADS2(k0 + 96);
      }
      MFMAS2();
      if (k0 + 64 < DIMM) LGKM0_FENCE();
    }
#undef LOADS2
#undef DSW2
#undef FRAGS2
#undef MFMAS2
  } else {
#define LOADS1(k0n)                                                  \
    do {                                                             \
      rA = *(const uint4*)(gA + (k0n));                              \
      rB0 = *(const uint4*)(gB + (k0n));                             \
      rB1 = *(const uint4*)(gB + 64 * DIMM + (k0n));                 \
    } while (0)
#define DSW1(p)                                                      \
    do {                                                             \
      *(uint4*)(&sAh[p][t8]) = rA;                                   \
      *(uint4*)(&sBh[p][t8]) = rB0;                                  \
      *(uint4*)(&sBh[p][t8 + 2048]) = rB1;                           \
    } while (0)
#define FRAGS1(p)                                                    \
    do {                                                             \
      _Pragma("unroll") for (int i = 0; i < 2; ++i)                  \
        ah[i] = __builtin_bit_cast(bf16x8,                           \
            *(const uint4*)(&sAh[p][(wm + i * 16 + l15) * 32 + quad * 8])); \
      _Pragma("unroll") for (int j = 0; j < 4; ++j)                  \
        bh[j] = __builtin_bit_cast(bf16x8,                           \
            *(const uint4*)(&sBh[p][(wn + j * 16 + l15) * 32 + quad * 8])); \
    } while (0)
#define MFMAS1()                                                     \
    do {                                                             \
      _Pragma("unroll") for (int i = 0; i < 2; ++i)                  \
        _Pragma("unroll") for (int j = 0; j < 4; ++j)                \
          acc[i][j] = MFMA(ah[i], bh[j], acc[i][j]);                 \
    } while (0)
    LOADS1(0);
    DSW1(0);
    LOADS1(32);
    LGKM0_FENCE();
    for (int k0 = 0; k0 < DIMM; k0 += 64) {
      bf16x8 ah[2], bh[4];
      FRAGS1(0);
      DSW1(1);
      if (k0 + 64 < DIMM) LOADS1(k0 + 64);
      MFMAS1();
      LGKM0_FENCE();
      FRAGS1(1);
      if (k0 + 64 < DIMM) {
        DSW1(0);
        if (k0 + 96 < DIMM) LOADS1(k0 + 96);
      }
      MFMAS1();
      if (k0 + 64 < DIMM) LGKM0_FENCE();
    }
#undef LOADS1
#undef DSW1
#undef FRAGS1
#undef MFMAS1
  }

  u16* oh = (mode == 0) ? qhi : khi;
  u16* ol = (mode == 0) ? qlo : klo;
#pragma unroll
  for (int i = 0; i < 2; ++i)
#pragma unroll
    for (int j = 0; j < 4; ++j)
#pragma unroll
      for (int r = 0; r < 4; ++r) {
        int grow = m0 + wm + i * 16 + quad * 4 + r;  // (b,l)
        int gcol = n0 + wn + j * 16 + l15;           // (h,d)
        float c = acc[i][j][r];
        int b = grow >> 10, ll = grow & 1023, h = gcol >> 6, d = gcol & 63;
        if (mode < 2) {
          int idx = ((b * NH + h) * LSEQ + ll) * HD + d;
          u16 hi = f2bf(c);
          oh[idx] = hi;
          ol[idx] = f2bf(c - bf2f(hi));
        } else if (mode == 2) {
          vT[((b * NH + h) * HD + d) * LSEQ + ll] = f2bf(c);
        } else {
          outp[grow * DIMM + gcol] = c + bias[gcol];
        }
      }
}

__global__ __launch_bounds__(256, 3) void gemm_qkv(
    const u16* __restrict__ AqH, const u16* __restrict__ AqL,
    const u16* __restrict__ AkH, const u16* __restrict__ AkL,
    const u16* __restrict__ Av, const u16* __restrict__ WqH,
    const u16* __restrict__ WqL, const u16* __restrict__ WkH,
    const u16* __restrict__ WkL, const u16* __restrict__ Wvr,
    const u16* __restrict__ Wpr, const u16* __restrict__ wbuf,
    u16* __restrict__ qhi, u16* __restrict__ qlo, u16* __restrict__ khi,
    u16* __restrict__ klo, u16* __restrict__ vT, float* __restrict__ outp,
    const float* __restrict__ bias) {
  gemm_body(blockIdx.z, AqH, AqL, AkH, AkL, Av, WqH, WqL, WkH, WkL, Wvr, Wpr,
            wbuf, qhi, qlo, khi, klo, vT, outp, bias);
}

__global__ __launch_bounds__(256, 3) void gemm_proj(
    const u16* __restrict__ AqH, const u16* __restrict__ AqL,
    const u16* __restrict__ AkH, const u16* __restrict__ AkL,
    const u16* __restrict__ Av, const u16* __restrict__ WqH,
    const u16* __restrict__ WqL, const u16* __restrict__ WkH,
    const u16* __restrict__ WkL, const u16* __restrict__ Wvr,
    const u16* __restrict__ Wpr, const u16* __restrict__ wbuf,
    u16* __restrict__ qhi, u16* __restrict__ qlo, u16* __restrict__ khi,
    u16* __restrict__ klo, u16* __restrict__ vT, float* __restrict__ outp,
    const float* __restrict__ bias) {
  gemm_body(3, AqH, AqL, AkH, AkL, Av, WqH, WqL, WkH, WkL, Wvr, Wpr,
            wbuf, qhi, qlo, khi, klo, vT, outp, bias);
}

// ---------- Kernel 2: attention core (round-7/round-5 best measured) -----
// Phase 1: reg-staged depth-2 pipeline into LDS with per-chunk lockstep
// barriers. NOTE (r8 finding): the barriers are load-bearing TRAFFIC
// SHAPING — all blocks of a (b,h) touch the same K chunk within a tight
// window, keeping the instantaneous L2 read set ~16KB x few groups.
// Removing them (direct-global K) explodes FETCH 17.6->245 MB even with
// the XCD swizzle (r8), as r1 did without it. Do not remove.
__global__ __launch_bounds__(256, 3) void attn_core(
    const u16* __restrict__ qhi, const u16* __restrict__ qlo,
    const u16* __restrict__ khi, const u16* __restrict__ klo,
    const u16* __restrict__ vT, const float* __restrict__ relk,
    const float* __restrict__ relv, float* __restrict__ attn_out,
    u16* __restrict__ wbuf) {
  // union: phase1 K-stage DOUBLE buffer (2 x 16 KB swizzled) then
  // Pb[16][1032] bf16 (33 KB)
  __shared__ __align__(16) u16 uni[16 * 1032];
  __shared__ float qrel[16][7];
  __shared__ float arel[16][7];
  __shared__ float rvt[7][64];
  __shared__ float red[4][16][4];

  // XCD-aware swizzle: 3072 blocks, 8 XCDs, 384 contiguous per XCD so
  // blocks sharing K/vT (same b,h) co-locate on one XCD's L2.
  const int Lb = blockIdx.x + 64 * (blockIdx.y + NH * blockIdx.z);
  const int flat = (Lb & 7) * 384 + (Lb >> 3);
  const int qt = flat & 63, h = (flat >> 6) % NH, b = flat / (64 * NH);
  const int q0 = qt * 16;
  const int tid = threadIdx.x, wave = tid >> 6, lane = tid & 63;
  const int quad = lane >> 4, l15 = lane & 15;
  const int bhd = b * NH + h;

  // ---- phase-1 staging geometry ----
  // thread t supplies K[row rs][cols cg*8..+8); slot index == t
  const int rs = tid >> 3;                  // 0..31
  const int cg = (tid & 7) ^ (rs & 7);      // XOR swizzle (conflict-free reads)
  const u16* gh = khi + (bhd * LSEQ + rs) * HD + cg * 8;
  const u16* gl = klo + (bhd * LSEQ + rs) * HD + cg * 8;
  u16* const wslot = uni + tid * 8;
  // read slots for this lane: row within chunk = wave*16+l15
  const int rowA = wave * 16 + l15;
  const int sw = rowA & 7;
  const int s0 = (rowA * 8 + (quad ^ sw)) * 8;        // u16 index (slot*8)
  const int s1 = (rowA * 8 + ((quad + 4) ^ sw)) * 8;

  // reg staging sets: chunk n lives in set[n&1] (A=even, B=odd)
  uint4 sA0, sA1, sA2, sA3, sB0, sB1, sB2, sB3;
#define LOADA(c)                                                     \
  do {                                                               \
    sA0 = *(const uint4*)(gh + (c) * (64 * HD));                     \
    sA1 = *(const uint4*)(gh + (c) * (64 * HD) + 32 * HD);           \
    sA2 = *(const uint4*)(gl + (c) * (64 * HD));                     \
    sA3 = *(const uint4*)(gl + (c) * (64 * HD) + 32 * HD);           \
  } while (0)
#define LOADB(c)                                                     \
  do {                                                               \
    sB0 = *(const uint4*)(gh + (c) * (64 * HD));                     \
    sB1 = *(const uint4*)(gh + (c) * (64 * HD) + 32 * HD);           \
    sB2 = *(const uint4*)(gl + (c) * (64 * HD));                     \
    sB3 = *(const uint4*)(gl + (c) * (64 * HD) + 32 * HD);           \
  } while (0)
#define DSWRITE_A(bufsel)                                            \
  do {                                                               \
    u16* d_ = wslot + (bufsel) * 8192;                               \
    *(uint4*)(d_) = sA0;                                             \
    *(uint4*)(d_ + 2048) = sA1;                                      \
    *(uint4*)(d_ + 4096) = sA2;                                      \
    *(uint4*)(d_ + 6144) = sA3;                                      \
  } while (0)
#define DSWRITE_B(bufsel)                                            \
  do {                                                               \
    u16* d_ = wslot + (bufsel) * 8192;                               \
    *(uint4*)(d_) = sB0;                                             \
    *(uint4*)(d_ + 2048) = sB1;                                      \
    *(uint4*)(d_ + 4096) = sB2;                                      \
    *(uint4*)(d_ + 6144) = sB3;                                      \
  } while (0)

  // Q fragments + prologue loads (chunks 0,1) issue first; their latency
  // hides under phase 0's qrel compute.
  const int qbase = (bhd * LSEQ + q0 + l15) * HD + quad * 8;
  bf16x8 ah0 = ld8bf(qhi + qbase);
  bf16x8 ah1 = ld8bf(qhi + qbase + 32);
  bf16x8 al0 = ld8bf(qlo + qbase);
  bf16x8 al1 = ld8bf(qlo + qbase + 32);
  LOADA(0);
  LOADB(1);

  // phase 0: rel_v -> LDS; qrel (vectorized); zero arel
  for (int t = tid; t < 7 * HD; t += 256) rvt[t >> 6][t & 63] = relv[t];
  if (tid < 112) {
    int q = tid / 7, rr = tid % 7;
    const u16* qp = qhi + (bhd * LSEQ + q0 + q) * HD;
    const u16* lp = qlo + (bhd * LSEQ + q0 + q) * HD;
    const float* tp = relk + rr * HD;
    float s = 0.f;
#pragma unroll
    for (int d8 = 0; d8 < HD; d8 += 8) {
      uint4 uh = *(const uint4*)(qp + d8);
      uint4 ul = *(const uint4*)(lp + d8);
      float4 t0 = *(const float4*)(tp + d8);
      float4 t1 = *(const float4*)(tp + d8 + 4);
      unsigned hh[4] = {uh.x, uh.y, uh.z, uh.w};
      unsigned lv[4] = {ul.x, ul.y, ul.z, ul.w};
      float tv[8] = {t0.x, t0.y, t0.z, t0.w, t1.x, t1.y, t1.z, t1.w};
#pragma unroll
      for (int m = 0; m < 4; ++m) {
        s += (bf2f((u16)(hh[m] & 0xffff)) + bf2f((u16)(lv[m] & 0xffff))) * tv[2 * m];
        s += (bf2f((u16)(hh[m] >> 16)) + bf2f((u16)(lv[m] >> 16))) * tv[2 * m + 1];
      }
    }
    qrel[q][rr] = s;
    arel[q][rr] = 0.f;
  }

  // prologue: chunk 0 -> buf0, then make it + phase-0 LDS writes visible.
  DSWRITE_A(0);
  asm volatile("s_waitcnt lgkmcnt(0)" ::: "memory");
  __builtin_amdgcn_sched_barrier(0);
  __builtin_amdgcn_s_barrier();

  // phase 1: S = Q K^T (hi/lo 3-term), depth-2 pipeline, fully unrolled
  f32x4 sc[16];
#pragma unroll
  for (int c = 0; c < 16; ++c) {
    const u16* cur = uni + (c & 1) * 8192;
    bf16x8 kh0 = ld8bf(cur + s0);
    bf16x8 kh1 = ld8bf(cur + s1);
    bf16x8 kl0 = ld8bf(cur + 4096 + s0);
    bf16x8 kl1 = ld8bf(cur + 4096 + s1);
    f32x4 e = {}, f = {};
    e = MFMA(ah0, kh0, e);
    f = MFMA(ah1, kh1, f);
    e = MFMA(ah0, kl0, e);
    f = MFMA(ah1, kl1, f);
    e = MFMA(al0, kh0, e);
    f = MFMA(al1, kh1, f);
    sc[c] = e + f;
    if (c < 14) {  // issue chunk c+2 into the set just consumed from LDS
      if ((c & 1) == 0) LOADA(c + 2); else LOADB(c + 2);
    }
    if (c < 15) {  // chunk c+1 regs -> buf[(c+1)&1]; then raw barrier
      if ((c & 1) == 0) DSWRITE_B(1); else DSWRITE_A(0);
      asm volatile("s_waitcnt lgkmcnt(0)" ::: "memory");
      __builtin_amdgcn_sched_barrier(0);
      __builtin_amdgcn_s_barrier();
    }
  }
#undef LOADA
#undef LOADB
#undef DSWRITE_A
#undef DSWRITE_B

  // phase 1.5: + rel scores, *8; per-row max
  const int colbase = wave * 16 + l15;        // col = colbase + c*64
  const int dbase = colbase - q0 - quad * 4;  // d = dbase + c*64 - r
  float mrow[4] = {-3.4e38f, -3.4e38f, -3.4e38f, -3.4e38f};
#pragma unroll
  for (int c = 0; c < 16; ++c)
#pragma unroll
    for (int r = 0; r < 4; ++r) {
      int d = dbase + c * 64 - r;
      int ri = d < -3 ? 0 : (d > 3 ? 6 : d + 3);
      float s = (sc[c][r] + qrel[quad * 4 + r][ri]) * 8.0f;
      sc[c][r] = s;
      mrow[r] = fmaxf(mrow[r], s);
    }
#pragma unroll
  for (int m = 1; m <= 8; m <<= 1)
#pragma unroll
    for (int r = 0; r < 4; ++r) mrow[r] = fmaxf(mrow[r], __shfl_xor(mrow[r], m));
  if (l15 < 4) {
    float mv = l15 == 0 ? mrow[0] : l15 == 1 ? mrow[1] : l15 == 2 ? mrow[2] : mrow[3];
    red[0][quad * 4 + l15][wave] = mv;
  }
  __syncthreads();
  float mx[4];
#pragma unroll
  for (int r = 0; r < 4; ++r) {
    int row = quad * 4 + r;
    mx[r] = fmaxf(fmaxf(red[0][row][0], red[0][row][1]),
                  fmaxf(red[0][row][2], red[0][row][3]));
  }

  // phase 2: exp + partial sums (total, d<=-3, d>=3)
  float sum[4] = {}, s0a[4] = {}, s6a[4] = {};
#pragma unroll
  for (int c = 0; c < 16; ++c)
#pragma unroll
    for (int r = 0; r < 4; ++r) {
      float e = __expf(sc[c][r] - mx[r]);
      sc[c][r] = e;
      int d = dbase + c * 64 - r;
      sum[r] += e;
      if (d <= -3) s0a[r] += e;
      if (d >= 3) s6a[r] += e;
    }
#pragma unroll
  for (int m = 1; m <= 8; m <<= 1)
#pragma unroll
    for (int r = 0; r < 4; ++r) {
      sum[r] += __shfl_xor(sum[r], m);
      s0a[r] += __shfl_xor(s0a[r], m);
      s6a[r] += __shfl_xor(s6a[r], m);
    }
  if (l15 < 4) {
    int row = quad * 4 + l15;
    float sv = l15 == 0 ? sum[0] : l15 == 1 ? sum[1] : l15 == 2 ? sum[2] : sum[3];
    float a0 = l15 == 0 ? s0a[0] : l15 == 1 ? s0a[1] : l15 == 2 ? s0a[2] : s0a[3];
    float a6 = l15 == 0 ? s6a[0] : l15 == 1 ? s6a[1] : l15 == 2 ? s6a[2] : s6a[3];
    red[1][row][wave] = sv;
    red[2][row][wave] = a0;
    red[3][row][wave] = a6;
  }
  __syncthreads();
  float rn[4];
#pragma unroll
  for (int r = 0; r < 4; ++r) {
    int row = quad * 4 + r;
    float s = red[1][row][0] + red[1][row][1] + red[1][row][2] + red[1][row][3];
    rn[r] = 1.0f / s;
    if (wave == 0 && l15 == 0) {
      float t0 = red[2][row][0] + red[2][row][1] + red[2][row][2] + red[2][row][3];
      float t6 = red[3][row][0] + red[3][row][1] + red[3][row][2] + red[3][row][3];
      arel[row][0] = t0 * rn[r];
      arel[row][6] = t6 * rn[r];
    }
  }

  // phase 2c: normalize -> Pb (bf16, LDS) + singleton buckets
#pragma unroll
  for (int c = 0; c < 16; ++c) {
    int col = colbase + c * 64;
#pragma unroll
    for (int r = 0; r < 4; ++r) {
      int row = quad * 4 + r;
      float p = sc[c][r] * rn[r];
      uni[row * 1032 + col] = f2bf(p);
      int d = dbase + c * 64 - r;
      if (d >= -2 && d <= 2) arel[row][d + 3] = p;
    }
  }
  __syncthreads();

  // phase 2d: coalesced fp32 attn store from Pb (float4/thread/row)
  {
    float* aob = attn_out + ((size_t)(bhd * LSEQ + q0)) * LSEQ;
#pragma unroll
    for (int row = 0; row < 16; ++row) {
      uint2 u = *(const uint2*)&uni[row * 1032 + tid * 4];
      float4 f = {bf2f((u16)(u.x & 0xffff)), bf2f((u16)(u.x >> 16)),
                  bf2f((u16)(u.y & 0xffff)), bf2f((u16)(u.y >> 16))};
      *(float4*)(aob + row * LSEQ + tid * 4) = f;
    }
  }

  // phase 3: W1 = P @ V (wave -> 16 d-cols) + W2 = arel @ rel_v
  {
    const u16* vb = vT + (bhd * HD + wave * 16 + l15) * LSEQ;
    f32x4 acc0 = {}, acc1 = {};
#pragma unroll 4
    for (int kk = 0; kk < LSEQ; kk += 64) {
      int ak = kk + quad * 8;
      bf16x8 aP0 = __builtin_bit_cast(bf16x8, *(const uint4*)&uni[l15 * 1032 + ak]);
      bf16x8 bV0 = ld8bf(vb + ak);
      acc0 = MFMA(aP0, bV0, acc0);
      bf16x8 aP1 = __builtin_bit_cast(bf16x8, *(const uint4*)&uni[l15 * 1032 + ak + 32]);
      bf16x8 bV1 = ld8bf(vb + ak + 32);
      acc1 = MFMA(aP1, bV1, acc1);
    }
    f32x4 acc = acc0 + acc1;
    const int col = wave * 16 + l15;  // d
#pragma unroll
    for (int r = 0; r < 4; ++r) {
      int row = quad * 4 + r;  // q within tile
      float w2 = 0.f;
#pragma unroll
      for (int t = 0; t < 7; ++t) w2 += arel[row][t] * rvt[t][col];
      wbuf[(b * LSEQ + q0 + row) * DIMM + h * HD + col] = f2bf(acc[r] + w2);
    }
  }
}

extern "C" void kernel_launch(void* const* d_in, const int* in_sizes, int n_in,
                              void* d_out, int out_size, void* d_ws, size_t ws_size,
                              hipStream_t stream) {
  const float* q_in = (const float*)d_in[0];
  const float* k_in = (const float*)d_in[1];
  const float* v_in = (const float*)d_in[2];
  const float* Wq = (const float*)d_in[3];
  const float* Wk = (const float*)d_in[4];
  const float* Wv = (const float*)d_in[5];
  const float* Wp = (const float*)d_in[6];
  const float* bias = (const float*)d_in[7];
  const float* relk = (const float*)d_in[8];
  const float* relv = (const float*)d_in[9];
  float* out = (float*)d_out;

  u16* p = (u16*)d_ws;
  u16 *AqH = p, *AqL = AqH + NXE, *AkH = AqL + NXE, *AkL = AkH + NXE,
      *Av = AkL + NXE;
  u16 *WqH = Av + NXE, *WqL = WqH + NWE, *WkH = WqL + NWE, *WkL = WkH + NWE,
      *Wvr = WkL + NWE, *Wpr = Wvr + NWE;
  u16 *qhi = Wpr + NWE, *qlo = qhi + NXE, *khi = qlo + NXE, *klo = khi + NXE,
      *vT = klo + NXE, *wbuf = vT + NXE;

  convert<<<(3 * NXE + 4 * NWE) / 1024, 256, 0, stream>>>(
      q_in, k_in, v_in, Wq, Wk, Wv, Wp, AqH, AqL, AkH, AkL, Av, WqH, WqL, WkH,
      WkL, Wvr, Wpr);
  gemm_qkv<<<dim3(64, 6, 3), 256, 0, stream>>>(
      AqH, AqL, AkH, AkL, Av, WqH, WqL, WkH, WkL, Wvr, Wpr, wbuf, qhi, qlo,
      khi, klo, vT, out, bias);
  attn_core<<<dim3(64, NH, BATCH), 256, 0, stream>>>(
      qhi, qlo, khi, klo, vT, relk, relv, out + NXE, wbuf);
  gemm_proj<<<dim3(64, 6, 1), 256, 0, stream>>>(
      AqH, AqL, AkH, AkL, Av, WqH, WqL, WkH, WkL, Wvr, Wpr, wbuf, qhi, qlo,
      khi, klo, vT, out, bias);
}